// Round 1
// baseline (2903.540 us; speedup 1.0000x reference)
//
#include <hip/hip_runtime.h>

#define N_NODES 100000
#define N_EDGES 1600000
#define IN_F    256
#define OUT_F   128

// ---------------------------------------------------------------------------
// K1: support[M,128] = X[M,256] @ W[256,128], fp32 vector ALU (no fp32 MFMA).
// Block = 256 threads, tile = 64 rows x 128 cols, K staged in LDS chunks of 16.
// Per-thread micro-tile: 8 rows x 4 cols. Inner loop: 3x ds_read_b128 : 32 FMA.
// ---------------------------------------------------------------------------
__global__ __launch_bounds__(256) void gemm_support(const float* __restrict__ X,
                                                    const float* __restrict__ W,
                                                    float* __restrict__ support) {
    __shared__ float Xs[16][64];    // [k][row]  (transposed so row-dim is contiguous)
    __shared__ float Ws[16][128];   // [k][col]

    const int t    = threadIdx.x;
    const int tx   = t & 31;        // col group: cols 4*tx .. 4*tx+3
    const int ty   = t >> 5;        // row group: rows 8*ty .. 8*ty+7
    const int row0 = blockIdx.x * 64;

    float acc[8][4];
#pragma unroll
    for (int i = 0; i < 8; ++i)
#pragma unroll
        for (int j = 0; j < 4; ++j) acc[i][j] = 0.f;

    for (int k0 = 0; k0 < IN_F; k0 += 16) {
        // Stage X chunk: 64 rows x 16 k = 1024 floats, one float4 per thread.
        {
            const int r  = t >> 2;          // 0..63
            const int kk = (t & 3) * 4;     // 0,4,8,12
            const int gr = row0 + r;
            float4 xv = make_float4(0.f, 0.f, 0.f, 0.f);
            if (gr < N_NODES) xv = *(const float4*)&X[(size_t)gr * IN_F + k0 + kk];
            Xs[kk + 0][r] = xv.x;
            Xs[kk + 1][r] = xv.y;
            Xs[kk + 2][r] = xv.z;
            Xs[kk + 3][r] = xv.w;
        }
        // Stage W chunk: 16 k x 128 cols = 2048 floats, two float4 per thread.
        {
#pragma unroll
            for (int it = 0; it < 2; ++it) {
                const int idx = (it * 256 + t) * 4;   // 0..2044 step 4
                const int kk  = idx >> 7;
                const int cc  = idx & 127;
                *(float4*)&Ws[kk][cc] = *(const float4*)&W[(size_t)(k0 + kk) * OUT_F + cc];
            }
        }
        __syncthreads();
#pragma unroll
        for (int k = 0; k < 16; ++k) {
            const float4 a0 = *(const float4*)&Xs[k][ty * 8];
            const float4 a1 = *(const float4*)&Xs[k][ty * 8 + 4];
            const float4 b  = *(const float4*)&Ws[k][tx * 4];
            const float av[8] = {a0.x, a0.y, a0.z, a0.w, a1.x, a1.y, a1.z, a1.w};
            const float bv[4] = {b.x, b.y, b.z, b.w};
#pragma unroll
            for (int i = 0; i < 8; ++i)
#pragma unroll
                for (int j = 0; j < 4; ++j) acc[i][j] += av[i] * bv[j];
        }
        __syncthreads();
    }

#pragma unroll
    for (int i = 0; i < 8; ++i) {
        const int gr = row0 + ty * 8 + i;
        if (gr < N_NODES) {
            *(float4*)&support[(size_t)gr * OUT_F + tx * 4] =
                make_float4(acc[i][0], acc[i][1], acc[i][2], acc[i][3]);
        }
    }
}

// ---------------------------------------------------------------------------
// K2: out[n, f] = bias[f]  (d_out is poisoned to 0xAA before every launch)
// ---------------------------------------------------------------------------
__global__ __launch_bounds__(256) void init_bias(const float* __restrict__ bias,
                                                 float* __restrict__ out) {
    const int i = blockIdx.x * 256 + threadIdx.x;       // float4 index
    const int total4 = N_NODES * OUT_F / 4;             // 3.2M
    if (i < total4) {
        const float4 b = *(const float4*)&bias[(i & 31) * 4];
        ((float4*)out)[i] = b;
    }
}

// ---------------------------------------------------------------------------
// K3: COO scatter: out[row[e]] += val[e] * support[col[e]]
// 32 threads per edge, float4 gather + 4 hw fp32 atomics per thread.
// ---------------------------------------------------------------------------
__global__ __launch_bounds__(256) void scatter_edges(const int* __restrict__ arow,
                                                     const int* __restrict__ acol,
                                                     const float* __restrict__ aval,
                                                     const float* __restrict__ support,
                                                     float* __restrict__ out) {
    const long long t = (long long)blockIdx.x * 256 + threadIdx.x;
    const int e = (int)(t >> 5);
    const int f = ((int)t & 31) * 4;
    if (e < N_EDGES) {
        const int   r = arow[e];
        const int   c = acol[e];
        const float v = aval[e];
        const float4 s = *(const float4*)&support[(size_t)c * OUT_F + f];
        float* op = &out[(size_t)r * OUT_F + f];
        unsafeAtomicAdd(op + 0, v * s.x);
        unsafeAtomicAdd(op + 1, v * s.y);
        unsafeAtomicAdd(op + 2, v * s.z);
        unsafeAtomicAdd(op + 3, v * s.w);
    }
}

// ---------------------------------------------------------------------------
extern "C" void kernel_launch(void* const* d_in, const int* in_sizes, int n_in,
                              void* d_out, int out_size, void* d_ws, size_t ws_size,
                              hipStream_t stream) {
    const float* X    = (const float*)d_in[0];
    const int*   arow = (const int*)d_in[1];
    const int*   acol = (const int*)d_in[2];
    const float* aval = (const float*)d_in[3];
    const float* W    = (const float*)d_in[4];
    const float* bias = (const float*)d_in[5];
    float*       out  = (float*)d_out;
    float*       support = (float*)d_ws;   // 100000*128*4 = 51.2 MB scratch

    // K1: dense GEMM into workspace
    gemm_support<<<(N_NODES + 63) / 64, 256, 0, stream>>>(X, W, support);

    // K2: initialize output with bias
    init_bias<<<(N_NODES * OUT_F / 4 + 255) / 256, 256, 0, stream>>>(bias, out);

    // K3: edge scatter with hw fp32 atomics
    const long long threads = (long long)N_EDGES * 32;
    scatter_edges<<<(unsigned)((threads + 255) / 256), 256, 0, stream>>>(
        arow, acol, aval, support, out);
}

// Round 2
// 629.170 us; speedup vs baseline: 4.6149x; 4.6149x over previous
//
#include <hip/hip_runtime.h>

#define N_NODES 100000
#define N_EDGES 1600000
#define IN_F    256
#define OUT_F   128

// ---------------------------------------------------------------------------
// K1: support[M,128] = X[M,256] @ W[256,128], fp32 vector ALU (no fp32 MFMA).
// ---------------------------------------------------------------------------
__global__ __launch_bounds__(256) void gemm_support(const float* __restrict__ X,
                                                    const float* __restrict__ W,
                                                    float* __restrict__ support) {
    __shared__ float Xs[16][64];    // [k][row]
    __shared__ float Ws[16][128];   // [k][col]

    const int t    = threadIdx.x;
    const int tx   = t & 31;        // col group: cols 4*tx .. 4*tx+3
    const int ty   = t >> 5;        // row group: rows 8*ty .. 8*ty+7
    const int row0 = blockIdx.x * 64;

    float acc[8][4];
#pragma unroll
    for (int i = 0; i < 8; ++i)
#pragma unroll
        for (int j = 0; j < 4; ++j) acc[i][j] = 0.f;

    for (int k0 = 0; k0 < IN_F; k0 += 16) {
        {
            const int r  = t >> 2;
            const int kk = (t & 3) * 4;
            const int gr = row0 + r;
            float4 xv = make_float4(0.f, 0.f, 0.f, 0.f);
            if (gr < N_NODES) xv = *(const float4*)&X[(size_t)gr * IN_F + k0 + kk];
            Xs[kk + 0][r] = xv.x;
            Xs[kk + 1][r] = xv.y;
            Xs[kk + 2][r] = xv.z;
            Xs[kk + 3][r] = xv.w;
        }
        {
#pragma unroll
            for (int it = 0; it < 2; ++it) {
                const int idx = (it * 256 + t) * 4;
                const int kk  = idx >> 7;
                const int cc  = idx & 127;
                *(float4*)&Ws[kk][cc] = *(const float4*)&W[(size_t)(k0 + kk) * OUT_F + cc];
            }
        }
        __syncthreads();
#pragma unroll
        for (int k = 0; k < 16; ++k) {
            const float4 a0 = *(const float4*)&Xs[k][ty * 8];
            const float4 a1 = *(const float4*)&Xs[k][ty * 8 + 4];
            const float4 b  = *(const float4*)&Ws[k][tx * 4];
            const float av[8] = {a0.x, a0.y, a0.z, a0.w, a1.x, a1.y, a1.z, a1.w};
            const float bv[4] = {b.x, b.y, b.z, b.w};
#pragma unroll
            for (int i = 0; i < 8; ++i)
#pragma unroll
                for (int j = 0; j < 4; ++j) acc[i][j] += av[i] * bv[j];
        }
        __syncthreads();
    }

#pragma unroll
    for (int i = 0; i < 8; ++i) {
        const int gr = row0 + ty * 8 + i;
        if (gr < N_NODES) {
            *(float4*)&support[(size_t)gr * OUT_F + tx * 4] =
                make_float4(acc[i][0], acc[i][1], acc[i][2], acc[i][3]);
        }
    }
}

// ---------------------------------------------------------------------------
// CSR build: zero counts -> histogram -> exclusive scan -> fill (col,val) packed
// ---------------------------------------------------------------------------
__global__ __launch_bounds__(256) void zero_counts(int* __restrict__ counts) {
    const int i = blockIdx.x * 256 + threadIdx.x;
    if (i < N_NODES) counts[i] = 0;
}

__global__ __launch_bounds__(256) void hist_rows(const int* __restrict__ arow,
                                                 int* __restrict__ counts) {
    const int e = blockIdx.x * 256 + threadIdx.x;
    if (e < N_EDGES) atomicAdd(&counts[arow[e]], 1);
}

// Single-block exclusive scan over counts[N_NODES] -> row_start, cursor.
__global__ __launch_bounds__(1024) void scan_counts(const int* __restrict__ counts,
                                                    int* __restrict__ row_start,
                                                    int* __restrict__ cursor) {
    __shared__ int wsum[16];
    __shared__ int s_carry;
    const int t    = threadIdx.x;
    const int lane = t & 63;
    const int wid  = t >> 6;
    if (t == 0) s_carry = 0;
    __syncthreads();

    for (int base = 0; base < N_NODES; base += 1024) {
        const int i = base + t;
        const int v = (i < N_NODES) ? counts[i] : 0;
        // inclusive scan within wave (64 lanes)
        int x = v;
#pragma unroll
        for (int off = 1; off < 64; off <<= 1) {
            const int y = __shfl_up(x, off, 64);
            if (lane >= off) x += y;
        }
        if (lane == 63) wsum[wid] = x;
        __syncthreads();
        if (wid == 0 && lane < 16) {
            int w = wsum[lane];
#pragma unroll
            for (int off = 1; off < 16; off <<= 1) {
                const int y = __shfl_up(w, off, 64);
                if (lane >= off) w += y;
            }
            wsum[lane] = w;   // inclusive scan of wave sums
        }
        __syncthreads();
        const int waveoff = wid ? wsum[wid - 1] : 0;
        const int excl = s_carry + waveoff + x - v;
        if (i < N_NODES) { row_start[i] = excl; cursor[i] = excl; }
        __syncthreads();
        if (t == 0) s_carry += wsum[15];
        __syncthreads();
    }
}

__global__ __launch_bounds__(256) void fill_csr(const int* __restrict__ arow,
                                                const int* __restrict__ acol,
                                                const float* __restrict__ aval,
                                                int* __restrict__ cursor,
                                                int2* __restrict__ epack) {
    const int e = blockIdx.x * 256 + threadIdx.x;
    if (e < N_EDGES) {
        const int r = arow[e];
        const int pos = atomicAdd(&cursor[r], 1);
        epack[pos] = make_int2(acol[e], __float_as_int(aval[e]));
    }
}

// ---------------------------------------------------------------------------
// K5: gather — 32 lanes per row, each lane owns 4 output features (float4).
// out[r] = bias + sum_e val * support[col]
// ---------------------------------------------------------------------------
__global__ __launch_bounds__(256) void gather_rows(const int* __restrict__ row_start,
                                                   const int* __restrict__ counts,
                                                   const int2* __restrict__ epack,
                                                   const float* __restrict__ support,
                                                   const float* __restrict__ bias,
                                                   float* __restrict__ out) {
    const int t = threadIdx.x;
    const int g = t >> 5;               // row group within block: 0..7
    const int l = t & 31;               // lane within group
    const int r = blockIdx.x * 8 + g;
    if (r >= N_NODES) return;

    const int start = row_start[r];
    const int deg   = counts[r];

    float4 acc = *(const float4*)&bias[l * 4];

    int i = 0;
    for (; i + 4 <= deg; i += 4) {
        const int2 e0 = epack[start + i + 0];
        const int2 e1 = epack[start + i + 1];
        const int2 e2 = epack[start + i + 2];
        const int2 e3 = epack[start + i + 3];
        const float4 s0 = *(const float4*)&support[(size_t)e0.x * OUT_F + l * 4];
        const float4 s1 = *(const float4*)&support[(size_t)e1.x * OUT_F + l * 4];
        const float4 s2 = *(const float4*)&support[(size_t)e2.x * OUT_F + l * 4];
        const float4 s3 = *(const float4*)&support[(size_t)e3.x * OUT_F + l * 4];
        const float v0 = __int_as_float(e0.y);
        const float v1 = __int_as_float(e1.y);
        const float v2 = __int_as_float(e2.y);
        const float v3 = __int_as_float(e3.y);
        acc.x = fmaf(v0, s0.x, fmaf(v1, s1.x, fmaf(v2, s2.x, fmaf(v3, s3.x, acc.x))));
        acc.y = fmaf(v0, s0.y, fmaf(v1, s1.y, fmaf(v2, s2.y, fmaf(v3, s3.y, acc.y))));
        acc.z = fmaf(v0, s0.z, fmaf(v1, s1.z, fmaf(v2, s2.z, fmaf(v3, s3.z, acc.z))));
        acc.w = fmaf(v0, s0.w, fmaf(v1, s1.w, fmaf(v2, s2.w, fmaf(v3, s3.w, acc.w))));
    }
    for (; i < deg; ++i) {
        const int2 e = epack[start + i];
        const float4 s = *(const float4*)&support[(size_t)e.x * OUT_F + l * 4];
        const float v = __int_as_float(e.y);
        acc.x = fmaf(v, s.x, acc.x);
        acc.y = fmaf(v, s.y, acc.y);
        acc.z = fmaf(v, s.z, acc.z);
        acc.w = fmaf(v, s.w, acc.w);
    }

    *(float4*)&out[(size_t)r * OUT_F + l * 4] = acc;
}

// ---------------------------------------------------------------------------
extern "C" void kernel_launch(void* const* d_in, const int* in_sizes, int n_in,
                              void* d_out, int out_size, void* d_ws, size_t ws_size,
                              hipStream_t stream) {
    const float* X    = (const float*)d_in[0];
    const int*   arow = (const int*)d_in[1];
    const int*   acol = (const int*)d_in[2];
    const float* aval = (const float*)d_in[3];
    const float* W    = (const float*)d_in[4];
    const float* bias = (const float*)d_in[5];
    float*       out  = (float*)d_out;

    // Workspace layout (bytes):
    //   [0, 51.2M)              support   (N_NODES*OUT_F floats)
    //   then counts / row_start / cursor  (N_NODES ints each)
    //   then epack                        (N_EDGES int2 = 12.8 MB)
    char* ws = (char*)d_ws;
    float* support  = (float*)ws;                       ws += (size_t)N_NODES * OUT_F * 4;
    int*   counts   = (int*)ws;                         ws += (size_t)N_NODES * 4;
    int*   row_startp = (int*)ws;                       ws += (size_t)N_NODES * 4;
    int*   cursor   = (int*)ws;                         ws += (size_t)N_NODES * 4;
    int2*  epack    = (int2*)ws;

    // Dense GEMM into workspace
    gemm_support<<<(N_NODES + 63) / 64, 256, 0, stream>>>(X, W, support);

    // CSR build
    zero_counts<<<(N_NODES + 255) / 256, 256, 0, stream>>>(counts);
    hist_rows<<<(N_EDGES + 255) / 256, 256, 0, stream>>>(arow, counts);
    scan_counts<<<1, 1024, 0, stream>>>(counts, row_startp, cursor);
    fill_csr<<<(N_EDGES + 255) / 256, 256, 0, stream>>>(arow, acol, aval, cursor, epack);

    // Gather: 8 rows per block of 256 threads
    gather_rows<<<(N_NODES + 7) / 8, 256, 0, stream>>>(
        row_startp, counts, epack, support, bias, out);
}